// Round 23
// baseline (540.694 us; speedup 1.0000x reference)
//
#include <hip/hip_runtime.h>

// ChamferDistance: B=4, N=M=8192, fp32 3-D points.
// R23: R20 (champion, 30.2 µs) + LDS DOUBLE-BUFFER, one barrier per stage.
// R22 post-mortem: pre-pack+DMA = 33.3 — the extra launch + packB kernel ate
// exactly what the fused kernel saved; in-kernel pack is fine, its
// SERIALIZATION is the cost (16 lockstep barriers, pack VALU serial with
// MFMA, global latency exposed). This round:
//  - 2 x 32 KB LDS buffers (128 KB/CU at 2 blocks -> occupancy unchanged);
//    pack stage s+1 into buf[(s+1)&1] while computing buf[s&1]; single
//    barrier per stage is sufficient (writers target the buffer whose
//    readers all passed the PREVIOUS barrier). 16 -> 9 barriers.
//  - T14 split: next stage's 6 floats loaded to regs BEFORE compute (latency
//    hides under MFMA), f2bf+ds_write after, then barrier.
// Geometry unchanged from R20: 512 thr, 128 rows/block, wave = row-tile(w&3)
// x col-half(w>>2), min3 pairing, grid 512 = 2 blocks/CU = 4 waves/SIMD,
// direct store, no atomics, no init, no workspace.
// Math verified since R4 (absmax 0.0156).

typedef short  short8 __attribute__((ext_vector_type(8)));
typedef float  f32x16 __attribute__((ext_vector_type(16)));

#define B_       4
#define NPT      8192
#define THREADS  512
#define NROWBLK  64              // 128 rows per block
#define STAGEPTS 1024            // B points per LDS stage (32 KB packed)
#define NSTAGE   (NPT / STAGEPTS)    // 8
#define PINF_I   0x7f800000

__device__ __forceinline__ unsigned short f2bf(float x) {
    unsigned u = __float_as_uint(x);
    u += 0x7fff + ((u >> 16) & 1);
    return (unsigned short)(u >> 16);
}
__device__ __forceinline__ float bf2f(unsigned short b) {
    return __uint_as_float(((unsigned)b) << 16);
}
#define PK2(a, b) ((((unsigned)(b)) << 16) | (unsigned)(a))

// Pack one row-point into the lane's A-fragment half (kg = lane>>5).
__device__ __forceinline__ short8 packA(const float* __restrict__ p, int kg) {
    const unsigned short one = 0x3f80;
    float x0 = p[0], x1 = p[1], x2 = p[2];
    unsigned short h0 = f2bf(x0), h1 = f2bf(x1), h2 = f2bf(x2);
    unsigned short l0 = f2bf(x0 - bf2f(h0)), l1 = f2bf(x1 - bf2f(h1)), l2 = f2bf(x2 - bf2f(h2));
    unsigned short m0 = f2bf(-2.f * bf2f(h0)), m1 = f2bf(-2.f * bf2f(h1)), m2 = f2bf(-2.f * bf2f(h2));
    unsigned short q0 = f2bf(-2.f * bf2f(l0)), q1 = f2bf(-2.f * bf2f(l1)), q2 = f2bf(-2.f * bf2f(l2));
    float n = x0*x0 + x1*x1 + x2*x2;
    unsigned short nh = f2bf(n), nl = f2bf(n - bf2f(nh));
    short8 r;
    if (kg == 0) {
        r[0] = (short)m0; r[1] = (short)m1; r[2] = (short)m2; r[3] = (short)q0;
        r[4] = (short)q1; r[5] = (short)q2; r[6] = (short)m0; r[7] = (short)m1;
    } else {
        r[0] = (short)m2; r[1] = (short)nh; r[2] = (short)nl; r[3] = (short)one;
        r[4] = (short)one; r[5] = 0; r[6] = 0; r[7] = 0;
    }
    return r;
}

// Pack one scanned point (y0,y1,y2) into split-K slot p of buffer buf.
__device__ __forceinline__ void packB_lds(uint4* __restrict__ buf, int p,
                                          float y0, float y1, float y2) {
    const unsigned short one = 0x3f80;
    unsigned short h0 = f2bf(y0), h1 = f2bf(y1), h2 = f2bf(y2);
    unsigned short l0 = f2bf(y0 - bf2f(h0));
    unsigned short l1 = f2bf(y1 - bf2f(h1));
    unsigned short l2 = f2bf(y2 - bf2f(h2));
    float n = y0*y0 + y1*y1 + y2*y2;
    unsigned short nh = f2bf(n), nl = f2bf(n - bf2f(nh));
    const int g = p >> 5, sl = p & 31;
    buf[g * 64 + sl]      = make_uint4(PK2(h0, h1), PK2(h2, h0), PK2(h1, h2), PK2(l0, l1));
    buf[g * 64 + 32 + sl] = make_uint4(PK2(l2, one), PK2(one, nh), PK2(nl, 0), PK2(0, 0));
}

__global__ __launch_bounds__(THREADS, 4)   // 4 waves/EU -> 2 blocks/CU, 128-reg cap
void cd_fused(const float* __restrict__ xyz1, const float* __restrict__ xyz2,
              float* __restrict__ out) {
    __shared__ uint4 ysh[2][STAGEPTS * 2];   // 2 x 32 KB double buffer

    int bid = blockIdx.x;
    const int rb   = bid & (NROWBLK - 1);  bid >>= 6;
    const int b    = bid & (B_ - 1);       bid >>= 2;
    const int pass = bid;                   // 0: dist1 (rows=cloud1), 1: dist2

    const float* __restrict__ xa = pass ? xyz2 : xyz1;   // row cloud
    const float* __restrict__ xb = pass ? xyz1 : xyz2;   // col cloud
    float* __restrict__ o = out + (size_t)pass * B_ * NPT;

    const int tid  = threadIdx.x;
    const int lane = tid & 63;
    const int w    = tid >> 6;             // 0..7
    const int rt   = w & 3;                // row-tile within block
    const int h    = w >> 2;               // column half (0 or 1)
    const int l31  = lane & 31;
    const int kg   = lane >> 5;

    const size_t bbase = (size_t)b * NPT;
    const int    myRow = rb * 128 + rt * 32;

    // In-register A fragment: lane packs its own row, keeps its k-half.
    short8 afrag = packA(xa + (bbase + myRow + l31) * 3, kg);

    f32x16 rmin;
    #pragma unroll
    for (int r = 0; r < 16; ++r) rmin[r] = __int_as_float(PINF_I);

    // Prologue: pack stage 0 into buffer 0 (2 points per thread).
    {
        const float* yp0 = xb + (bbase + 0 * STAGEPTS + tid) * 3;
        const float* yp1 = xb + (bbase + 0 * STAGEPTS + THREADS + tid) * 3;
        packB_lds(ysh[0], tid,           yp0[0], yp0[1], yp0[2]);
        packB_lds(ysh[0], THREADS + tid, yp1[0], yp1[1], yp1[2]);
    }
    __syncthreads();

    for (int s = 0; s < NSTAGE; ++s) {
        // T14 split: early-load next stage's 6 floats (latency under compute)
        float ya0 = 0.f, ya1 = 0.f, ya2 = 0.f, yb0 = 0.f, yb1 = 0.f, yb2 = 0.f;
        const bool more = (s + 1 < NSTAGE);
        if (more) {
            const float* yp0 = xb + (bbase + (size_t)(s + 1) * STAGEPTS + tid) * 3;
            const float* yp1 = xb + (bbase + (size_t)(s + 1) * STAGEPTS + THREADS + tid) * 3;
            ya0 = yp0[0]; ya1 = yp0[1]; ya2 = yp0[2];
            yb0 = yp1[0]; yb1 = yp1[1]; yb2 = yp1[2];
        }

        // Compute this wave's column half: 16 tiles = 8 min3 pairs.
        const unsigned short* bsh = (const unsigned short*)ysh[s & 1];
        #pragma unroll
        for (int pr = 0; pr < 8; ++pr) {
            const int t0 = h * 16 + pr * 2;
            short8 bf0 = *(const short8*)(bsh + (size_t)t0 * 512 + kg * 256 + l31 * 8);
            short8 bf1 = *(const short8*)(bsh + (size_t)(t0 + 1) * 512 + kg * 256 + l31 * 8);
            f32x16 z = {0.f};
            f32x16 accX = __builtin_amdgcn_mfma_f32_32x32x16_bf16(afrag, bf0, z, 0, 0, 0);
            f32x16 accY = __builtin_amdgcn_mfma_f32_32x32x16_bf16(afrag, bf1, z, 0, 0, 0);
            #pragma unroll
            for (int r = 0; r < 16; ++r)
                rmin[r] = fminf(fminf(accX[r], accY[r]), rmin[r]);   // v_min3_f32
        }

        // Pack next stage into the other buffer (safe: its readers passed the
        // previous barrier), then ONE barrier.
        if (more) {
            packB_lds(ysh[(s + 1) & 1], tid,           ya0, ya1, ya2);
            packB_lds(ysh[(s + 1) & 1], THREADS + tid, yb0, yb1, yb2);
        }
        __syncthreads();
    }

    // Cross-half combine via LDS (reuse ysh[0]; [rt][r][lane] conflict-free).
    float* csh = (float*)ysh[0];           // 4 * 16 * 64 floats = 16 KB
    if (h == 1) {
        #pragma unroll
        for (int r = 0; r < 16; ++r)
            csh[rt * 1024 + r * 64 + lane] = rmin[r];
    }
    __syncthreads();
    if (h == 0) {
        #pragma unroll
        for (int r = 0; r < 16; ++r) {
            float v = fminf(rmin[r], csh[rt * 1024 + r * 64 + lane]);
            v = fminf(v, __shfl_xor(v, 1, 64));
            v = fminf(v, __shfl_xor(v, 2, 64));
            v = fminf(v, __shfl_xor(v, 4, 64));
            v = fminf(v, __shfl_xor(v, 8, 64));
            v = fminf(v, __shfl_xor(v, 16, 64));
            if (l31 == 0) {
                int row = myRow + (r & 3) + 8 * (r >> 2) + 4 * kg;
                o[bbase + row] = fmaxf(v, 0.f);
            }
        }
    }
}

extern "C" void kernel_launch(void* const* d_in, const int* in_sizes, int n_in,
                              void* d_out, int out_size, void* d_ws, size_t ws_size,
                              hipStream_t stream) {
    const float* xyz1 = (const float*)d_in[0];
    const float* xyz2 = (const float*)d_in[1];
    // ONE launch, no workspace, no init, no atomics.
    cd_fused<<<2 * B_ * NROWBLK, THREADS, 0, stream>>>(xyz1, xyz2, (float*)d_out);
}

// Round 24
// 27.206 us; speedup vs baseline: 19.8742x; 19.8742x over previous
//
#include <hip/hip_runtime.h>

// ChamferDistance: B=4, N=M=8192, fp32 3-D points.
// R24: R20 (champion, 30.2 µs) with FAT BLOCKS to halve pack redundancy.
// R23 post-mortem: double-buffer+T14 spilled (540 µs, WRITE 1.4 GB) ->
// reverted per pre-commitment. R21 isolated that total in-kernel B-pack
// scales with grid (2x grid -> +9 µs). Inverse move: 1024-thread blocks,
// 256 rows/block (8 row-tiles x 2 col-halves = 16 waves), grid 256 =
// 1 block/CU = SAME 4 waves/SIMD as R20, but HALF the total pack work
// (1 pt/thread/stage). Everything else byte-for-byte R20: single 32 KB
// buffer, 2 barriers/stage, min3 pairing, split-K conflict-free LDS,
// direct store, no atomics, no init, no workspace.
// Math verified since R4 (absmax 0.0156): d = n1+n2-2x.y, hi/lo bf16 K=16;
// C layout 32x32: col=lane&31, row=(r&3)+8*(r>>2)+4*(lane>>5).

typedef short  short8 __attribute__((ext_vector_type(8)));
typedef float  f32x16 __attribute__((ext_vector_type(16)));

#define B_       4
#define NPT      8192
#define THREADS  1024
#define NROWBLK  32              // 256 rows per block
#define STAGEPTS 1024            // B points per LDS stage (32 KB packed)
#define NSTAGE   (NPT / STAGEPTS)    // 8
#define PINF_I   0x7f800000

__device__ __forceinline__ unsigned short f2bf(float x) {
    unsigned u = __float_as_uint(x);
    u += 0x7fff + ((u >> 16) & 1);
    return (unsigned short)(u >> 16);
}
__device__ __forceinline__ float bf2f(unsigned short b) {
    return __uint_as_float(((unsigned)b) << 16);
}
#define PK2(a, b) ((((unsigned)(b)) << 16) | (unsigned)(a))

// Pack one row-point into the lane's A-fragment half (kg = lane>>5).
__device__ __forceinline__ short8 packA(const float* __restrict__ p, int kg) {
    const unsigned short one = 0x3f80;
    float x0 = p[0], x1 = p[1], x2 = p[2];
    unsigned short h0 = f2bf(x0), h1 = f2bf(x1), h2 = f2bf(x2);
    unsigned short l0 = f2bf(x0 - bf2f(h0)), l1 = f2bf(x1 - bf2f(h1)), l2 = f2bf(x2 - bf2f(h2));
    unsigned short m0 = f2bf(-2.f * bf2f(h0)), m1 = f2bf(-2.f * bf2f(h1)), m2 = f2bf(-2.f * bf2f(h2));
    unsigned short q0 = f2bf(-2.f * bf2f(l0)), q1 = f2bf(-2.f * bf2f(l1)), q2 = f2bf(-2.f * bf2f(l2));
    float n = x0*x0 + x1*x1 + x2*x2;
    unsigned short nh = f2bf(n), nl = f2bf(n - bf2f(nh));
    short8 r;
    if (kg == 0) {
        r[0] = (short)m0; r[1] = (short)m1; r[2] = (short)m2; r[3] = (short)q0;
        r[4] = (short)q1; r[5] = (short)q2; r[6] = (short)m0; r[7] = (short)m1;
    } else {
        r[0] = (short)m2; r[1] = (short)nh; r[2] = (short)nl; r[3] = (short)one;
        r[4] = (short)one; r[5] = 0; r[6] = 0; r[7] = 0;
    }
    return r;
}

__global__ __launch_bounds__(THREADS, 4)   // 16 waves/block, 1 block/CU, 128-reg cap
void cd_fused(const float* __restrict__ xyz1, const float* __restrict__ xyz2,
              float* __restrict__ out) {
    __shared__ uint4 ysh[STAGEPTS * 2];    // 32 KB: split-K packed B stage

    int bid = blockIdx.x;
    const int rb   = bid & (NROWBLK - 1);  bid >>= 5;
    const int b    = bid & (B_ - 1);       bid >>= 2;
    const int pass = bid;                   // 0: dist1 (rows=cloud1), 1: dist2

    const float* __restrict__ xa = pass ? xyz2 : xyz1;   // row cloud
    const float* __restrict__ xb = pass ? xyz1 : xyz2;   // col cloud
    float* __restrict__ o = out + (size_t)pass * B_ * NPT;

    const int tid  = threadIdx.x;
    const int lane = tid & 63;
    const int w    = tid >> 6;             // 0..15
    const int rt   = w & 7;                // row-tile within block (8)
    const int h    = w >> 3;               // column half (0 or 1)
    const int l31  = lane & 31;
    const int kg   = lane >> 5;
    const unsigned short one = 0x3f80;

    const size_t bbase = (size_t)b * NPT;
    const int    myRow = rb * 256 + rt * 32;

    // In-register A fragment: lane packs its own row, keeps its k-half.
    short8 afrag = packA(xa + (bbase + myRow + l31) * 3, kg);

    f32x16 rmin;
    #pragma unroll
    for (int r = 0; r < 16; ++r) rmin[r] = __int_as_float(PINF_I);

    const unsigned short* bsh = (const unsigned short*)ysh;

    for (int s = 0; s < NSTAGE; ++s) {
        // Pack 1024 B points into LDS (ONE per thread), split-K layout:
        // group g = p>>5: uint4 [g*64 + slot] = k0..7, [g*64+32+slot] = k8..15
        {
            const int p = tid;
            const float* yp = xb + (bbase + (size_t)s * STAGEPTS + p) * 3;
            float y0 = yp[0], y1 = yp[1], y2 = yp[2];
            unsigned short h0 = f2bf(y0), h1 = f2bf(y1), h2 = f2bf(y2);
            unsigned short l0 = f2bf(y0 - bf2f(h0));
            unsigned short l1 = f2bf(y1 - bf2f(h1));
            unsigned short l2 = f2bf(y2 - bf2f(h2));
            float n = y0*y0 + y1*y1 + y2*y2;
            unsigned short nh = f2bf(n), nl = f2bf(n - bf2f(nh));
            const int g = p >> 5, sl = p & 31;
            ysh[g * 64 + sl]      = make_uint4(PK2(h0, h1), PK2(h2, h0), PK2(h1, h2), PK2(l0, l1));
            ysh[g * 64 + 32 + sl] = make_uint4(PK2(l2, one), PK2(one, nh), PK2(nl, 0), PK2(0, 0));
        }
        __syncthreads();

        // This wave's column half: 16 tiles = 8 min3 pairs of pure LDS compute.
        #pragma unroll
        for (int pr = 0; pr < 8; ++pr) {
            const int t0 = h * 16 + pr * 2;
            short8 bf0 = *(const short8*)(bsh + (size_t)t0 * 512 + kg * 256 + l31 * 8);
            short8 bf1 = *(const short8*)(bsh + (size_t)(t0 + 1) * 512 + kg * 256 + l31 * 8);
            f32x16 z = {0.f};
            f32x16 accX = __builtin_amdgcn_mfma_f32_32x32x16_bf16(afrag, bf0, z, 0, 0, 0);
            f32x16 accY = __builtin_amdgcn_mfma_f32_32x32x16_bf16(afrag, bf1, z, 0, 0, 0);
            #pragma unroll
            for (int r = 0; r < 16; ++r)
                rmin[r] = fminf(fminf(accX[r], accY[r]), rmin[r]);   // v_min3_f32
        }
        __syncthreads();
    }

    // Cross-half combine via LDS (reuse ysh; [rt][r][lane] = conflict-free).
    float* csh = (float*)ysh;              // 8 * 16 * 64 floats = 32 KB
    if (h == 1) {
        #pragma unroll
        for (int r = 0; r < 16; ++r)
            csh[rt * 1024 + r * 64 + lane] = rmin[r];
    }
    __syncthreads();
    if (h == 0) {
        #pragma unroll
        for (int r = 0; r < 16; ++r) {
            float v = fminf(rmin[r], csh[rt * 1024 + r * 64 + lane]);
            v = fminf(v, __shfl_xor(v, 1, 64));
            v = fminf(v, __shfl_xor(v, 2, 64));
            v = fminf(v, __shfl_xor(v, 4, 64));
            v = fminf(v, __shfl_xor(v, 8, 64));
            v = fminf(v, __shfl_xor(v, 16, 64));
            if (l31 == 0) {
                int row = myRow + (r & 3) + 8 * (r >> 2) + 4 * kg;
                o[bbase + row] = fmaxf(v, 0.f);
            }
        }
    }
}

extern "C" void kernel_launch(void* const* d_in, const int* in_sizes, int n_in,
                              void* d_out, int out_size, void* d_ws, size_t ws_size,
                              hipStream_t stream) {
    const float* xyz1 = (const float*)d_in[0];
    const float* xyz2 = (const float*)d_in[1];
    // ONE launch, no workspace, no init, no atomics.
    cd_fused<<<2 * B_ * NROWBLK, THREADS, 0, stream>>>(xyz1, xyz2, (float*)d_out);
}